// Round 2
// 3251.327 us; speedup vs baseline: 1.0404x; 1.0404x over previous
//
#include <hip/hip_runtime.h>
#include <math.h>

typedef unsigned short u16;
typedef __attribute__((ext_vector_type(8))) __bf16 bf16x8;
typedef __attribute__((ext_vector_type(4))) float f32x4;
typedef __attribute__((ext_vector_type(4))) u16 u16x4;

#define DIM    2048
#define NLAT   256
#define HEADS  8
#define DHEAD  64
#define INNER  512
#define TT     24
#define NN     49
#define SEQ    (TT*NN)        // 1176
#define BATCH  16
#define MROWS  (BATCH*SEQ)    // 18816
#define LROWS  (BATCH*NLAT)   // 4096
#define KEYS   (SEQ+NLAT)     // 1432
#define KPAD   1536
#define FF     (DIM*4)        // 8192
#define SCALE  0.125f

__device__ __forceinline__ u16 f2bf(float f) {
  union { float f; unsigned u; } c; c.f = f;
  unsigned r = c.u + 0x7FFFu + ((c.u >> 16) & 1u);
  return (u16)(r >> 16);
}

#define AS1(p) ((__attribute__((address_space(1))) void*)(p))
#define AS3(p) ((__attribute__((address_space(3))) void*)(p))

// ---------------------------------------------------------------------------
// Weight transpose + fp32->bf16: W (K x N) -> Wt (N x K) bf16
// ---------------------------------------------------------------------------
__global__ __launch_bounds__(256) void transpose_bf16(
    const float* __restrict__ W, u16* __restrict__ Wt, int K, int N)
{
  __shared__ float tile[32][33];
  const int tx = threadIdx.x & 31, ty = threadIdx.x >> 5;   // 32 x 8
  const int n0 = blockIdx.x * 32, k0 = blockIdx.y * 32;
  #pragma unroll
  for (int p = 0; p < 4; ++p)
    tile[ty + p*8][tx] = W[(size_t)(k0 + ty + p*8) * N + n0 + tx];
  __syncthreads();
  #pragma unroll
  for (int p = 0; p < 4; ++p)
    Wt[(size_t)(n0 + ty + p*8) * K + k0 + tx] = f2bf(tile[tx][ty + p*8]);
}

// ---------------------------------------------------------------------------
// LayerNorm over rows of length DIM. OUT = u16 (bf16) or float.
// ---------------------------------------------------------------------------
template<typename OUT>
__global__ __launch_bounds__(256) void ln_row(
    const float* __restrict__ x, const float* __restrict__ s,
    const float* __restrict__ b, OUT* __restrict__ y)
{
  const size_t row = blockIdx.x;
  const int tid = threadIdx.x;
  const f32x4* xr = (const f32x4*)(x + row * DIM);
  f32x4 v0 = xr[tid], v1 = xr[tid + 256];
  float sum = v0[0]+v0[1]+v0[2]+v0[3] + v1[0]+v1[1]+v1[2]+v1[3];
  float sq  = v0[0]*v0[0]+v0[1]*v0[1]+v0[2]*v0[2]+v0[3]*v0[3]
            + v1[0]*v1[0]+v1[1]*v1[1]+v1[2]*v1[2]+v1[3]*v1[3];
  #pragma unroll
  for (int o = 32; o > 0; o >>= 1) { sum += __shfl_down(sum, o); sq += __shfl_down(sq, o); }
  __shared__ float red[18];
  const int wave = tid >> 6, lane = tid & 63;
  if (lane == 0) { red[wave] = sum; red[8 + wave] = sq; }
  __syncthreads();
  if (tid == 0) {
    float S = red[0]+red[1]+red[2]+red[3];
    float Q = red[8]+red[9]+red[10]+red[11];
    float m = S * (1.0f/DIM);
    float var = Q * (1.0f/DIM) - m*m;
    red[16] = m; red[17] = rsqrtf(var + 1e-5f);
  }
  __syncthreads();
  const float m = red[16], inv = red[17];
  const f32x4* s4 = (const f32x4*)s; const f32x4* b4 = (const f32x4*)b;
  f32x4 o0 = (v0 - m) * inv * s4[tid]       + b4[tid];
  f32x4 o1 = (v1 - m) * inv * s4[tid + 256] + b4[tid + 256];
  if (sizeof(OUT) == 2) {
    u16x4 a = {f2bf(o0[0]), f2bf(o0[1]), f2bf(o0[2]), f2bf(o0[3])};
    u16x4 c = {f2bf(o1[0]), f2bf(o1[1]), f2bf(o1[2]), f2bf(o1[3])};
    u16x4* yr = (u16x4*)((u16*)y + row * DIM);
    yr[tid] = a; yr[tid + 256] = c;
  } else {
    f32x4* yr = (f32x4*)((float*)y + row * DIM);
    yr[tid] = o0; yr[tid + 256] = o1;
  }
}

// ---------------------------------------------------------------------------
// bf16 MFMA GEMM, BK=64, XCD-aware swizzle, XOR-permuted LDS chunks.
// A: M x lda bf16 (use K cols from koff).  Bt: N x ldb bf16.
// EPI: 0=f32 C; 1=f32 C+seg; 2=f32 C+res; 3=bf16 gelu(C); 4=bf16 C;
//      5=f32 partial to Cv + z*M*N (split-K via blockIdx.z).
// Launch: gridDim.y padded so gridDim.x*gridDim.y % 8 == 0.
// ---------------------------------------------------------------------------
template<int EPI>
__global__ __launch_bounds__(256) void gemm64(
    const u16* __restrict__ A, const u16* __restrict__ Bt, void* __restrict__ Cv,
    const float* __restrict__ res, const float* __restrict__ seg,
    int M, int N, int Klen, int lda, int ldb)
{
  __shared__ u16 lA[128 * 64];
  __shared__ u16 lB[128 * 64];
  const int tid  = threadIdx.x;
  const int wave = tid >> 6, lane = tid & 63;
  const int quad = lane >> 4, l16 = lane & 15;
  const int srow = lane >> 3, chunk = lane & 7;
  const int pchunk = chunk ^ srow;              // XOR bank spread

  // XCD-aware swizzle: id%8 = XCD (round-robin); same-XCD consecutive ids
  // walk column tiles innermost over a contiguous row range -> A L2 reuse.
  const int nx = gridDim.x;
  const int ny = M >> 7;
  const int id = blockIdx.y * nx + blockIdx.x;
  const int nseq = (nx * gridDim.y) >> 3;
  const int W = (id & 7) * nseq + (id >> 3);
  const int row_t = W / nx, col_t = W - row_t * nx;
  if (row_t >= ny) return;
  const int rowBase = row_t * 128, colBase = col_t * 128;
  const int wr = (wave >> 1) * 64, wc = (wave & 1) * 64;
  const int koff = (EPI == 5) ? blockIdx.z * Klen : 0;

  f32x4 acc[4][4] = {};

  for (int k0 = 0; k0 < Klen; k0 += 64) {
    #pragma unroll
    for (int i = 0; i < 4; ++i) {
      const int seg8 = wave * 4 + i;            // 0..15, wave-uniform
      const int row = seg8 * 8 + srow;
      const u16* gA = A  + (size_t)(rowBase + row) * lda + koff + k0 + pchunk * 8;
      const u16* gB = Bt + (size_t)(colBase + row) * ldb + koff + k0 + pchunk * 8;
      __builtin_amdgcn_global_load_lds(AS1(gA), AS3(&lA[seg8 * 512]), 16, 0, 0);
      __builtin_amdgcn_global_load_lds(AS1(gB), AS3(&lB[seg8 * 512]), 16, 0, 0);
    }
    __syncthreads();
    #pragma unroll
    for (int t = 0; t < 2; ++t) {
      bf16x8 af[4], bfr[4];
      #pragma unroll
      for (int i = 0; i < 4; ++i) {
        const int row = wr + i*16 + l16;
        af[i] = *(const bf16x8*)&lA[row*64 + (((t*4 + quad) ^ (row & 7)) * 8)];
      }
      #pragma unroll
      for (int j = 0; j < 4; ++j) {
        const int row = wc + j*16 + l16;
        bfr[j] = *(const bf16x8*)&lB[row*64 + (((t*4 + quad) ^ (row & 7)) * 8)];
      }
      #pragma unroll
      for (int i = 0; i < 4; ++i)
        #pragma unroll
        for (int j = 0; j < 4; ++j)
          acc[i][j] = __builtin_amdgcn_mfma_f32_16x16x32_bf16(af[i], bfr[j], acc[i][j], 0, 0, 0);
    }
    __syncthreads();
  }

  float* Pc = (EPI == 5) ? (float*)Cv + (size_t)blockIdx.z * ((size_t)M * N) : (float*)Cv;
  #pragma unroll
  for (int i = 0; i < 4; ++i) {
    #pragma unroll
    for (int j = 0; j < 4; ++j) {
      const int col = colBase + wc + j*16 + l16;
      #pragma unroll
      for (int r = 0; r < 4; ++r) {
        const int row = rowBase + wr + i*16 + quad*4 + r;
        const size_t idx = (size_t)row * N + col;
        float val = acc[i][j][r];
        if (EPI == 0) {
          Pc[idx] = val;
        } else if (EPI == 1) {
          const int t = (row % SEQ) / NN;
          Pc[idx] = val + seg[t * DIM + col];
        } else if (EPI == 2) {
          Pc[idx] = val + res[idx];
        } else if (EPI == 3) {
          float g = 0.5f * val * (1.0f + erff(val * 0.70710678118f));
          ((u16*)Cv)[idx] = f2bf(g);
        } else if (EPI == 4) {
          ((u16*)Cv)[idx] = f2bf(val);
        } else {
          Pc[idx] = val;
        }
      }
    }
  }
}

// ---------------------------------------------------------------------------
// ffn2 split-K combine: LAT += P[0] + P[1]
// ---------------------------------------------------------------------------
__global__ __launch_bounds__(256) void combine_ffn(
    const float* __restrict__ P, float* __restrict__ LAT)
{
  const size_t i = (size_t)blockIdx.x * 256 + threadIdx.x;   // f32x4 units
  f32x4 a = ((const f32x4*)P)[i];
  f32x4 b = ((const f32x4*)(P + (size_t)LROWS * DIM))[i];
  ((f32x4*)LAT)[i] = ((f32x4*)LAT)[i] + a + b;
}

// ---------------------------------------------------------------------------
// Stage-A windowed attention on fused QKV fp32 (row stride 1536:
// q at +0, k at +512, v at +1024).
// v2: one block per (b,t,h); K/V staged to LDS via global_load_lds (async,
// no VGPR round-trip); per-key loop reads LDS broadcast rows (conflict-free).
// Removes the per-key dependent global-load latency chain that held the
// old version at 13.5% VALUBusy / 250 us.
// ---------------------------------------------------------------------------
__global__ __launch_bounds__(64) void attn_local(
    const float* __restrict__ QKV, u16* __restrict__ out)
{
  __shared__ __align__(16) float lK[NN * DHEAD];   // 12544 B
  __shared__ __align__(16) float lV[NN * DHEAD];   // 12544 B
  const int bt = blockIdx.x;
  const int h  = blockIdx.y;
  const int b  = bt / TT, t = bt % TT;
  const int lane = threadIdx.x;
  const size_t base = ((size_t)b * SEQ + t * NN) * 1536 + h * DHEAD;  // floats

  // ---- stage K,V (49 rows x 64 f32 each) into LDS: 784 f32x4 per matrix ----
  #pragma unroll
  for (int i = 0; i < 12; ++i) {                 // 12*64 = 768 f32x4
    const int idx = i * 64 + lane;
    const int row = idx >> 4, d4 = idx & 15;
    const float* gK = QKV + base + (size_t)row * 1536 + 512  + d4 * 4;
    const float* gV = QKV + base + (size_t)row * 1536 + 1024 + d4 * 4;
    __builtin_amdgcn_global_load_lds(AS1(gK), AS3(&((f32x4*)lK)[i * 64]), 16, 0, 0);
    __builtin_amdgcn_global_load_lds(AS1(gV), AS3(&((f32x4*)lV)[i * 64]), 16, 0, 0);
  }
  if (lane < 16) {                               // tail: row 48, f32x4 768..783
    const float* gK = QKV + base + (size_t)48 * 1536 + 512  + lane * 4;
    const float* gV = QKV + base + (size_t)48 * 1536 + 1024 + lane * 4;
    __builtin_amdgcn_global_load_lds(AS1(gK), AS3(&((f32x4*)lK)[768]), 16, 0, 0);
    __builtin_amdgcn_global_load_lds(AS1(gV), AS3(&((f32x4*)lV)[768]), 16, 0, 0);
  }

  // ---- load q row (lane = query index, clamped for idle lanes) ----
  const int qi = (lane < NN) ? lane : (NN - 1);
  const f32x4* qr = (const f32x4*)(QKV + base + (size_t)qi * 1536);
  f32x4 qv[16];
  #pragma unroll
  for (int d = 0; d < 16; ++d) qv[d] = qr[d] * SCALE;

  asm volatile("s_waitcnt vmcnt(0)" ::: "memory");
  __syncthreads();

  // ---- key loop from LDS (broadcast reads: all lanes same address) ----
  f32x4 ov[16] = {};
  float l = 0.f;
  #pragma unroll 7
  for (int j = 0; j < NN; ++j) {
    const f32x4* kr = (const f32x4*)(lK + j * DHEAD);
    float s0 = 0.f, s1 = 0.f, s2 = 0.f, s3 = 0.f;
    #pragma unroll
    for (int d = 0; d < 16; ++d) {
      f32x4 k4 = kr[d];
      s0 += qv[d][0] * k4[0]; s1 += qv[d][1] * k4[1];
      s2 += qv[d][2] * k4[2]; s3 += qv[d][3] * k4[3];
    }
    const float e = __expf((s0 + s1) + (s2 + s3));
    l += e;
    const f32x4* vr = (const f32x4*)(lV + j * DHEAD);
    #pragma unroll
    for (int d = 0; d < 16; ++d) ov[d] += e * vr[d];
  }

  if (lane < NN) {
    const float rl = 1.0f / l;
    u16* orow = out + ((size_t)b * SEQ + t * NN + lane) * INNER + h * DHEAD;
    #pragma unroll
    for (int d = 0; d < 16; ++d) {
      f32x4 o = ov[d] * rl;
      u16x4 u = {f2bf(o[0]), f2bf(o[1]), f2bf(o[2]), f2bf(o[3])};
      *(u16x4*)(orow + d * 4) = u;
    }
  }
}

// ---------------------------------------------------------------------------
// Cross-attn scores: E[bh][i][j] = exp(SCALE * q_i . k_j) bf16, pad keys = 0.
// Q from fused QKVL (stride 1536, q at +0, k at +512); x-keys from KVXB
// (stride 1024, k at +0).
// ---------------------------------------------------------------------------
__global__ __launch_bounds__(256) void egemm(
    const u16* __restrict__ QKVL, const u16* __restrict__ KVXB, u16* __restrict__ E)
{
  __shared__ u16 lA[128 * 32];
  __shared__ u16 lB[128 * 32];
  const int tid = threadIdx.x;
  const int wave = tid >> 6, lane = tid & 63;
  const int quad = lane >> 4, l16 = lane & 15;
  const int srow = lane >> 2, chunk = lane & 3;
  const int ntile = blockIdx.x, mtile = blockIdx.y, bh = blockIdx.z;
  const int b = bh >> 3, h = bh & 7;
  const int wr = (wave >> 1) * 64, wc = (wave & 1) * 64;

  f32x4 acc[4][4] = {};

  for (int k0 = 0; k0 < DHEAD; k0 += 32) {
    #pragma unroll
    for (int c = 0; c < 2; ++c) {
      const int s = wave * 2 + c;
      const int r = s * 16 + srow;
      const u16* gA = QKVL + ((size_t)b * NLAT + mtile * 128 + r) * 1536
                           + h * DHEAD + k0 + chunk * 8;
      const int key = min(ntile * 128 + r, KEYS - 1);
      const u16* gB = (key < SEQ)
        ? KVXB + ((size_t)b * SEQ + key) * 1024 + h * DHEAD + k0 + chunk * 8
        : QKVL + ((size_t)b * NLAT + (key - SEQ)) * 1536 + 512 + h * DHEAD + k0 + chunk * 8;
      __builtin_amdgcn_global_load_lds(AS1(gA), AS3(&lA[s * 512]), 16, 0, 0);
      __builtin_amdgcn_global_load_lds(AS1(gB), AS3(&lB[s * 512]), 16, 0, 0);
    }
    __syncthreads();
    bf16x8 af[4], bfg[4];
    #pragma unroll
    for (int i = 0; i < 4; ++i)
      af[i] = *(const bf16x8*)&lA[(wr + i*16 + l16) * 32 + quad * 8];
    #pragma unroll
    for (int j = 0; j < 4; ++j)
      bfg[j] = *(const bf16x8*)&lB[(wc + j*16 + l16) * 32 + quad * 8];
    #pragma unroll
    for (int i = 0; i < 4; ++i)
      #pragma unroll
      for (int j = 0; j < 4; ++j)
        acc[i][j] = __builtin_amdgcn_mfma_f32_16x16x32_bf16(af[i], bfg[j], acc[i][j], 0, 0, 0);
    __syncthreads();
  }

  u16* Eb = E + ((size_t)bh * NLAT + mtile * 128) * KPAD;
  #pragma unroll
  for (int i = 0; i < 4; ++i) {
    #pragma unroll
    for (int j = 0; j < 4; ++j) {
      const int col = ntile * 128 + wc + j*16 + l16;
      #pragma unroll
      for (int r = 0; r < 4; ++r) {
        const int row = wr + i*16 + quad*4 + r;
        const float v = acc[i][j][r] * SCALE;
        Eb[(size_t)row * KPAD + col] = (col < KEYS) ? f2bf(__expf(v)) : (u16)0;
      }
    }
  }
}

// ---------------------------------------------------------------------------
// V transpose: VT[bh][64][KPAD] bf16, pad keys zeroed. V from KVXB (+512) /
// QKVL (+1024).
// ---------------------------------------------------------------------------
__global__ __launch_bounds__(256) void vt_build(
    const u16* __restrict__ KVXB, const u16* __restrict__ QKVL, u16* __restrict__ VT)
{
  __shared__ u16 tile[32][33];
  const int tx = threadIdx.x & 31, ty = threadIdx.x >> 5;
  const int kt = blockIdx.x, dt = blockIdx.y, bh = blockIdx.z;
  const int b = bh >> 3, h = bh & 7;
  #pragma unroll
  for (int p = 0; p < 4; ++p) {
    const int key = kt * 32 + ty + p * 8;
    const int dim = dt * 32 + tx;
    u16 v = 0;
    if (key < KEYS) {
      const u16* src = (key < SEQ)
        ? KVXB + ((size_t)b * SEQ + key) * 1024 + 512 + h * DHEAD + dim
        : QKVL + ((size_t)b * NLAT + (key - SEQ)) * 1536 + 1024 + h * DHEAD + dim;
      v = *src;
    }
    tile[ty + p * 8][tx] = v;
  }
  __syncthreads();
  #pragma unroll
  for (int p = 0; p < 4; ++p) {
    const int dim = dt * 32 + ty + p * 8;
    const int key = kt * 32 + tx;
    VT[((size_t)bh * DHEAD + dim) * KPAD + key] = tile[tx][ty + p * 8];
  }
}

// ---------------------------------------------------------------------------
// O = normalize(E @ V), row-sums via ones-fragment MFMA. Grid: 256 blocks.
// ---------------------------------------------------------------------------
__global__ __launch_bounds__(256) void ogemm(
    const u16* __restrict__ E, const u16* __restrict__ VT, u16* __restrict__ out)
{
  __shared__ u16 lA[128 * 32];
  __shared__ u16 lB[64 * 32];
  const int tid = threadIdx.x;
  const int wave = tid >> 6, lane = tid & 63;
  const int quad = lane >> 4, l16 = lane & 15;
  const int srow = lane >> 2, chunk = lane & 3;
  const int mtile = blockIdx.x & 1, bh = blockIdx.x >> 1;
  const int b = bh >> 3, h = bh & 7;

  const u16* Eb = E + ((size_t)bh * NLAT + mtile * 128) * KPAD;
  const u16* Vb = VT + (size_t)bh * DHEAD * KPAD;

  f32x4 acc[2][4] = {};
  f32x4 lsum[2] = {};
  bf16x8 ones;
  #pragma unroll
  for (int z = 0; z < 8; ++z) ones[z] = (__bf16)1.0f;

  for (int k0 = 0; k0 < KPAD; k0 += 32) {
    #pragma unroll
    for (int c = 0; c < 2; ++c) {
      const int s = wave * 2 + c;
      const int r = s * 16 + srow;
      __builtin_amdgcn_global_load_lds(AS1(Eb + (size_t)r * KPAD + k0 + chunk * 8),
                                       AS3(&lA[s * 512]), 16, 0, 0);
    }
    {
      const int r = wave * 16 + srow;
      __builtin_amdgcn_global_load_lds(AS1(Vb + (size_t)r * KPAD + k0 + chunk * 8),
                                       AS3(&lB[wave * 512]), 16, 0, 0);
    }
    __syncthreads();
    bf16x8 af[2], bfg[4];
    #pragma unroll
    for (int i = 0; i < 2; ++i)
      af[i] = *(const bf16x8*)&lA[(wave*32 + i*16 + l16) * 32 + quad * 8];
    #pragma unroll
    for (int j = 0; j < 4; ++j)
      bfg[j] = *(const bf16x8*)&lB[(j*16 + l16) * 32 + quad * 8];
    #pragma unroll
    for (int i = 0; i < 2; ++i) {
      lsum[i] = __builtin_amdgcn_mfma_f32_16x16x32_bf16(af[i], ones, lsum[i], 0, 0, 0);
      #pragma unroll
      for (int j = 0; j < 4; ++j)
        acc[i][j] = __builtin_amdgcn_mfma_f32_16x16x32_bf16(af[i], bfg[j], acc[i][j], 0, 0, 0);
    }
    __syncthreads();
  }

  #pragma unroll
  for (int i = 0; i < 2; ++i) {
    #pragma unroll
    for (int r = 0; r < 4; ++r) {
      const int row = mtile * 128 + wave * 32 + i * 16 + quad * 4 + r;
      const float rl = 1.0f / lsum[i][r];
      #pragma unroll
      for (int j = 0; j < 4; ++j) {
        const int col = j * 16 + l16;
        out[((size_t)b * NLAT + row) * INNER + h * DHEAD + col] = f2bf(acc[i][j][r] * rl);
      }
    }
  }
}

__global__ __launch_bounds__(256) void lat_init(
    const float* __restrict__ latents, float* __restrict__ lat)
{
  const size_t i = (size_t)blockIdx.x * 256 + threadIdx.x;  // f32x4 units
  const size_t row = i >> 9, c4 = i & 511;
  ((f32x4*)lat)[i] = ((const f32x4*)latents)[(row & (NLAT - 1)) * 512 + c4];
}

// ---------------------------------------------------------------------------
// Launcher.
// ---------------------------------------------------------------------------
extern "C" void kernel_launch(void* const* d_in, const int* in_sizes, int n_in,
                              void* d_out, int out_size, void* d_ws, size_t ws_size,
                              hipStream_t stream) {
  const float* x        = (const float*)d_in[0];
  const float* g_norm_s = (const float*)d_in[1];
  const float* g_norm_b = (const float*)d_in[2];
  const float* g_wq     = (const float*)d_in[3];
  const float* g_wkv    = (const float*)d_in[4];
  const float* g_wo     = (const float*)d_in[5];
  const float* seg_emb  = (const float*)d_in[6];
  const float* latents  = (const float*)d_in[7];
  const float* a_nm_s   = (const float*)d_in[8];
  const float* a_nm_b   = (const float*)d_in[9];
  const float* a_nl_s   = (const float*)d_in[10];
  const float* a_nl_b   = (const float*)d_in[11];
  const float* a_wq     = (const float*)d_in[12];
  const float* a_wkv    = (const float*)d_in[13];
  const float* a_wo     = (const float*)d_in[14];
  const float* f_n_s    = (const float*)d_in[15];
  const float* f_n_b    = (const float*)d_in[16];
  const float* f_w1     = (const float*)d_in[17];
  const float* f_w2     = (const float*)d_in[18];
  const float* out_n_s  = (const float*)d_in[19];
  const float* out_n_b  = (const float*)d_in[20];

  size_t off = 0;
  auto alloc = [&](size_t bytes) -> char* {
    char* p = (char*)d_ws + off;
    off += (bytes + 255) & ~(size_t)255;
    return p;
  };
  float* XBUF  = (float*)alloc((size_t)MROWS * DIM * 4);      // 154.1 MB
  u16*   TBUF  = (u16*)  alloc((size_t)MROWS * DIM * 2);      // 77.1 MB
  u16*   LMBUF = (u16*)  alloc((size_t)LROWS * DIM * 2);      // 16.8 MB
  float* LAT   = (float*)alloc((size_t)LROWS * DIM * 4);      // 33.6 MB
  u16*   AOBUF = (u16*)  alloc((size_t)MROWS * INNER * 2);    // 19.3 MB
  u16*   WT    = (u16*)  alloc((size_t)37748736 * 2);         // 75.5 MB
  u16*   HBUF  = (u16*)  alloc((size_t)LROWS * FF * 2);       // 67.1 MB
  char*  U     = alloc((size_t)178000000);                    // union region
  (void)ws_size; (void)n_in; (void)in_sizes; (void)out_size;

  // stage A view: fused QKV fp32 (18816 x 1536) = 115.6 MB
  float* QKV = (float*)U;
  // layer-phase views
  u16* EBUF  = (u16*)U;                                           // 100.7 MB
  float* PART = (float*)U;                                        // 67.1 MB (after ogemm)
  u16* VT    = (u16*)(U + (size_t)128 * NLAT * KPAD * 2);         // 25.2 MB
  u16* QKVL  = (u16*)(U + (size_t)128 * NLAT * KPAD * 2 + (size_t)128 * DHEAD * KPAD * 2);
  u16* KVXB  = (u16*)((char*)QKVL + (size_t)LROWS * 1536 * 2);    // 38.5 MB

  u16* Wcat = WT;                       // 1536 x 2048 (q rows 0-511, kv 512-1535)
  u16* WKVT = WT + (size_t)512 * 2048;  // alias: kv part of Wcat
  u16* WOT  = WT + 3145728;             // 2048 x 512
  u16* W1T  = WT + 4194304;             // 8192 x 2048
  u16* W2T  = WT + 20971520;            // 2048 x 8192

  const dim3 b256(256);
  auto ypad = [](int nx, int ny) { while ((nx * ny) & 7) ny++; return ny; };

  // ---- Stage A ----
  transpose_bf16<<<dim3(INNER/32, DIM/32), b256, 0, stream>>>(g_wq,  Wcat, DIM, INNER);
  transpose_bf16<<<dim3(2*INNER/32, DIM/32), b256, 0, stream>>>(g_wkv, WKVT, DIM, 2*INNER);
  transpose_bf16<<<dim3(DIM/32, INNER/32), b256, 0, stream>>>(g_wo,  WOT,  INNER, DIM);
  ln_row<u16><<<MROWS, b256, 0, stream>>>(x, g_norm_s, g_norm_b, TBUF);
  gemm64<0><<<dim3(12, ypad(12, 147)), b256, 0, stream>>>(TBUF, Wcat, QKV, nullptr, nullptr, MROWS, 1536, DIM, DIM, DIM);
  attn_local<<<dim3(BATCH*TT, HEADS), dim3(64), 0, stream>>>(QKV, AOBUF);
  gemm64<1><<<dim3(16, 147), b256, 0, stream>>>(AOBUF, WOT, XBUF, nullptr, seg_emb, MROWS, DIM, INNER, INNER, INNER);
  lat_init<<<(LROWS*DIM/4)/256, b256, 0, stream>>>(latents, LAT);

  // ---- DEPTH layers ----
  for (int l = 0; l < 3; ++l) {
    transpose_bf16<<<dim3(INNER/32, DIM/32), b256, 0, stream>>>(a_wq + (size_t)l*DIM*INNER, Wcat, DIM, INNER);
    transpose_bf16<<<dim3(2*INNER/32, DIM/32), b256, 0, stream>>>(a_wkv + (size_t)l*DIM*2*INNER, WKVT, DIM, 2*INNER);
    transpose_bf16<<<dim3(DIM/32, INNER/32), b256, 0, stream>>>(a_wo + (size_t)l*INNER*DIM, WOT, INNER, DIM);
    transpose_bf16<<<dim3(FF/32, DIM/32), b256, 0, stream>>>(f_w1 + (size_t)l*DIM*FF, W1T, DIM, FF);
    transpose_bf16<<<dim3(DIM/32, FF/32), b256, 0, stream>>>(f_w2 + (size_t)l*FF*DIM, W2T, FF, DIM);

    ln_row<u16><<<MROWS, b256, 0, stream>>>(XBUF, a_nm_s + l*DIM, a_nm_b + l*DIM, TBUF);
    ln_row<u16><<<LROWS, b256, 0, stream>>>(LAT, a_nl_s + l*DIM, a_nl_b + l*DIM, LMBUF);

    gemm64<4><<<dim3(8, 147), b256, 0, stream>>>(TBUF, WKVT, KVXB, nullptr, nullptr, MROWS, 1024, DIM, DIM, DIM);
    gemm64<4><<<dim3(12, 32), b256, 0, stream>>>(LMBUF, Wcat, QKVL, nullptr, nullptr, LROWS, 1536, DIM, DIM, DIM);

    vt_build<<<dim3(KPAD/32, 2, 128), b256, 0, stream>>>(KVXB, QKVL, VT);
    egemm<<<dim3(KPAD/128, 2, 128), b256, 0, stream>>>(QKVL, KVXB, EBUF);
    ogemm<<<dim3(256), b256, 0, stream>>>(EBUF, VT, AOBUF);

    gemm64<2><<<dim3(16, 32), b256, 0, stream>>>(AOBUF + (size_t)0, WOT, LAT, LAT, nullptr, LROWS, DIM, INNER, INNER, INNER);

    ln_row<u16><<<LROWS, b256, 0, stream>>>(LAT, f_n_s + l*DIM, f_n_b + l*DIM, LMBUF);
    gemm64<3><<<dim3(64, 32), b256, 0, stream>>>(LMBUF, W1T, HBUF, nullptr, nullptr, LROWS, FF, DIM, DIM, DIM);
    gemm64<5><<<dim3(16, 32, 2), b256, 0, stream>>>(HBUF, W2T, PART, nullptr, nullptr, LROWS, DIM, FF/2, FF, FF);
    combine_ffn<<<(LROWS*DIM/4)/256, b256, 0, stream>>>(PART, LAT);
  }

  ln_row<float><<<LROWS, b256, 0, stream>>>(LAT, out_n_s, out_n_b, (float*)d_out);
}